// Round 9
// baseline (893.093 us; speedup 1.0000x reference)
//
#include <hip/hip_runtime.h>

// R12: sort-free fused segment-sum — direct global f32 atomicAdd into out.
// Evidence (R11 profile): bucket_reduce 472us at 3.2% HBM / MLP=1 (latency
// disaster); sort stages measured ~213us by subtraction, and ~210-240us in
// EVERY structure tried (R8 global-atomic sort, R10 LDS bucket sort+CSR,
// R11 bucket sort). Useful traffic is only ~220MB (~35us). So: delete the
// sort. Per edge: one coalesced 256B w-read (16 lanes x float4) + 64
// fire-and-forget f32 atomics to out[row][0..63] (consecutive addresses,
// same-line RMW at L2). No return values -> no vmcnt stall on the atomic
// path; loads for 4 edges hoisted ahead of the atomic burst (MLP=5).
// Grid 12500x256, full occupancy, zero workspace.
// Falsifier: if dur >= ~350us, L2 atomic throughput (<~75G/s) is the wall
// -> revert to pipeline and attack the sort's tiny-grid/contention issues.

#define UN 4   // edges per thread

__global__ __launch_bounds__(256) void fused_atomic_spmm(
    const int* __restrict__ edge0, const float4* __restrict__ w4,
    float* __restrict__ out, int E)
{
    int g = blockIdx.x * blockDim.x + threadIdx.x;
    int f = g & 15;                    // float4 slot within the 64-f row
    int e0 = (g >> 4) * UN;            // first edge of this thread's group
    if (e0 >= E) return;

    if (e0 + UN <= E) {
        // 16B edge-row load (same dword group for 16 lanes -> HW broadcast)
        int4 er = *reinterpret_cast<const int4*>(&edge0[e0]);
        // 4 independent 256B-coalesced w reads (lanes 0-15 cover one edge)
        float4 v0 = w4[(size_t)(e0 + 0) * 16 + f];
        float4 v1 = w4[(size_t)(e0 + 1) * 16 + f];
        float4 v2 = w4[(size_t)(e0 + 2) * 16 + f];
        float4 v3 = w4[(size_t)(e0 + 3) * 16 + f];
        float* p0 = &out[(size_t)er.x * 64 + f * 4];
        float* p1 = &out[(size_t)er.y * 64 + f * 4];
        float* p2 = &out[(size_t)er.z * 64 + f * 4];
        float* p3 = &out[(size_t)er.w * 64 + f * 4];
        // 16 fire-and-forget atomics; 16 lanes x 4 floats = full 256B row
        // region per edge, consecutive addresses across lanes.
        atomicAdd(p0 + 0, v0.x); atomicAdd(p0 + 1, v0.y);
        atomicAdd(p0 + 2, v0.z); atomicAdd(p0 + 3, v0.w);
        atomicAdd(p1 + 0, v1.x); atomicAdd(p1 + 1, v1.y);
        atomicAdd(p1 + 2, v1.z); atomicAdd(p1 + 3, v1.w);
        atomicAdd(p2 + 0, v2.x); atomicAdd(p2 + 1, v2.y);
        atomicAdd(p2 + 2, v2.z); atomicAdd(p2 + 3, v2.w);
        atomicAdd(p3 + 0, v3.x); atomicAdd(p3 + 1, v3.y);
        atomicAdd(p3 + 2, v3.z); atomicAdd(p3 + 3, v3.w);
    } else {
        for (int e = e0; e < E; ++e) {
            int row = edge0[e];
            float4 v = w4[(size_t)e * 16 + f];
            float* p = &out[(size_t)row * 64 + f * 4];
            atomicAdd(p + 0, v.x); atomicAdd(p + 1, v.y);
            atomicAdd(p + 2, v.z); atomicAdd(p + 3, v.w);
        }
    }
}

extern "C" void kernel_launch(void* const* d_in, const int* in_sizes, int n_in,
                              void* d_out, int out_size, void* d_ws, size_t ws_size,
                              hipStream_t stream) {
    const int*   edge   = (const int*)d_in[0];     // (2,E) int32; rows = edge[0,:]
    const float* edge_w = (const float*)d_in[1];   // (E, 64) float32
    int E = in_sizes[0] / 2;
    // out_size is in floats (N = out_size/64 across all prior rounds)
    (void)hipMemsetAsync(d_out, 0, (size_t)out_size * sizeof(float), stream);

    int groups  = (E + UN - 1) / UN;               // 200000 for E=800000
    long long threads = (long long)groups * 16;    // 3.2M
    int blocks  = (int)((threads + 255) / 256);    // 12500
    fused_atomic_spmm<<<blocks, 256, 0, stream>>>(edge, (const float4*)edge_w,
                                                  (float*)d_out, E);
}

// Round 10
// 576.643 us; speedup vs baseline: 1.5488x; 1.5488x over previous
//
#include <hip/hip_runtime.h>

// R13: bucket pipeline with latency-fixed reduce + store-direct scatter.
// Measured so far: global atomics = 75 G/s (R12: 684us for 51.2M) -> per-
// element atomics out; R11 reduce 472us was MLP=1 (shfl->load->LDS-atomic
// serial); fixed harness cost ~120-210us/iter (fills) means our kernels in
// the 352us best were ~230us: scatter ~65-90 + reduce ~75-140 dominate.
// R13 changes:
//  - scatter_direct: fire-and-forget int2 stores at gb[bucket]+rank (gb in
//    LDS; no staging; stores don't stall the wave).
//  - bucket_reduce: ONE RECORD PER LANE; each lane walks its edge's 256B w
//    row as 2x8 independent float4 loads (MLP 8) + 64 ds_add_f32 into
//    acc[64][65] (pad -> bank=(row+c)%32, conflict-free-ish). Bucket =
//    row>>6 -> 782 blocks (~3/CU).
// Constraints: N <= 65536; within-row order arbitrary (tol 0.0625).

#define SHIFT  6                  // bucket = row >> 6 (64 rows/bucket)
#define WROWS  64
#define CEDGE  4096               // edges per hist/scatter block (1024 thr x 4)
#define SELEM  16                 // scan elems/thread
#define STILE  4096               // scan tile: 256 threads x 16

// K1: per-chunk bucket histogram -> cnt[bucket * nblk + blk]
__global__ __launch_bounds__(1024) void bucket_hist(
    const int* __restrict__ edge0, int* __restrict__ cnt,
    int E, int nblk, int NB)
{
    __shared__ int lh[1024];
    int t = threadIdx.x, blk = blockIdx.x;
    lh[t] = 0;
    __syncthreads();
    int idx4 = blk * 1024 + t;
    int base = idx4 * 4;
    if (base + 3 < E) {
        int4 r = ((const int4*)edge0)[idx4];
        atomicAdd(&lh[r.x >> SHIFT], 1);
        atomicAdd(&lh[r.y >> SHIFT], 1);
        atomicAdd(&lh[r.z >> SHIFT], 1);
        atomicAdd(&lh[r.w >> SHIFT], 1);
    } else {
        for (int i = base; i < E && i < base + 4; ++i)
            atomicAdd(&lh[edge0[i] >> SHIFT], 1);
    }
    __syncthreads();
    if (t < NB) cnt[t * nblk + blk] = lh[t];
}

// K2/K3: 2-dispatch exclusive scan of M ints (M=153272 -> 38 tiles <= 64).
__global__ __launch_bounds__(256) void scan_partial(
    const int* __restrict__ a, int* __restrict__ tileSum, int M)
{
    __shared__ int wsum[4];
    int t = threadIdx.x;
    int base = blockIdx.x * STILE + t * SELEM;
    int s = 0;
    #pragma unroll
    for (int k = 0; k < SELEM; ++k) {
        int i = base + k;
        if (i < M) s += a[i];
    }
    for (int off = 1; off < 64; off <<= 1) s += __shfl_xor(s, off);
    if ((t & 63) == 0) wsum[t >> 6] = s;
    __syncthreads();
    if (t == 0) tileSum[blockIdx.x] = wsum[0] + wsum[1] + wsum[2] + wsum[3];
}

__global__ __launch_bounds__(256) void scan_final(
    const int* __restrict__ a, const int* __restrict__ tileSum,
    int* __restrict__ ax, int M, int numTiles)
{
    __shared__ int wtot[4];
    __shared__ int tilePre;
    int t = threadIdx.x;
    int lane = t & 63, wv = t >> 6;

    if (t < 64) {                            // wave 0: scan tile sums
        int v0 = (t < numTiles) ? tileSum[t] : 0;
        int v = v0;
        #pragma unroll
        for (int off = 1; off < 64; off <<= 1) {
            int u = __shfl_up(v, off);
            if (t >= off) v += u;
        }
        if (t == blockIdx.x) tilePre = v - v0;   // exclusive prefix of this tile
    }

    int base = blockIdx.x * STILE + t * SELEM;
    int c[SELEM]; int s = 0;
    #pragma unroll
    for (int k = 0; k < SELEM; ++k) {
        int i = base + k;
        c[k] = (i < M) ? a[i] : 0;
        s += c[k];
    }
    int inc = s;
    #pragma unroll
    for (int off = 1; off < 64; off <<= 1) {
        int u = __shfl_up(inc, off);
        if (lane >= off) inc += u;
    }
    if (lane == 63) wtot[wv] = inc;
    __syncthreads();
    int wpre = 0;
    for (int w = 0; w < wv; ++w) wpre += wtot[w];
    int pre = tilePre + wpre + (inc - s);
    #pragma unroll
    for (int k = 0; k < SELEM; ++k) {
        int i = base + k;
        if (i < M) ax[i] = pre;
        pre += c[k];
    }
}

// K4: direct scatter — LDS rank + fire-and-forget int2 store at
// gb[bucket]+rank. gb LDS-resident kills the random offsets-gather.
__global__ __launch_bounds__(1024) void scatter_direct(
    const int* __restrict__ edge0, const int* __restrict__ cntX,
    int2* __restrict__ recs, int E, int nblk, int NB)
{
    __shared__ int lh[1024];
    __shared__ int gb[1024];
    int t = threadIdx.x, blk = blockIdx.x;
    lh[t] = 0;
    if (t < NB) gb[t] = cntX[t * nblk + blk];
    __syncthreads();
    int idx4 = blk * 1024 + t;
    int base = idx4 * 4;
    if (base + 3 < E) {
        int4 r = ((const int4*)edge0)[idx4];
        int b0 = r.x >> SHIFT, b1 = r.y >> SHIFT;
        int b2 = r.z >> SHIFT, b3 = r.w >> SHIFT;
        int k0 = atomicAdd(&lh[b0], 1);
        int k1 = atomicAdd(&lh[b1], 1);
        int k2 = atomicAdd(&lh[b2], 1);
        int k3 = atomicAdd(&lh[b3], 1);
        recs[gb[b0] + k0] = make_int2(r.x, base + 0);
        recs[gb[b1] + k1] = make_int2(r.y, base + 1);
        recs[gb[b2] + k2] = make_int2(r.z, base + 2);
        recs[gb[b3] + k3] = make_int2(r.w, base + 3);
    } else {
        for (int i = base; i < E && i < base + 4; ++i) {
            int rr = edge0[i];
            int b = rr >> SHIFT;
            int k = atomicAdd(&lh[b], 1);
            recs[gb[b] + k] = make_int2(rr, i);
        }
    }
}

// K5: one block per bucket (64 rows). One record per LANE: lane reads its
// edge's 64 floats as 2x8 independent float4 loads (MLP 8; 8 consecutive
// loads share a 128B line -> L1 hits after first), then 64 ds_add_f32 into
// acc[row&63][c] with +1 pad (bank=(row+c)%32). Dump coalesced.
__global__ __launch_bounds__(512) void bucket_reduce(
    const int* __restrict__ cntX, const int2* __restrict__ recs,
    const float4* __restrict__ w4, float* __restrict__ out,
    int E, int nblk, int NB, int N)
{
    __shared__ float acc[WROWS][65];
    int t = threadIdx.x, b = blockIdx.x;
    int S0 = cntX[b * nblk];
    int S1 = (b + 1 < NB) ? cntX[(b + 1) * nblk] : E;

    for (int i = t; i < WROWS * 65; i += 512) ((float*)acc)[i] = 0.f;
    __syncthreads();

    for (int k = S0 + t; k < S1; k += 512) {
        int2 rec = recs[k];
        int lr = rec.x & (WROWS - 1);
        const float4* __restrict__ wp = w4 + (size_t)rec.y * 16;
        float4 v[8];
        #pragma unroll
        for (int f = 0; f < 8; ++f) v[f] = wp[f];
        #pragma unroll
        for (int f = 0; f < 8; ++f) {
            atomicAdd(&acc[lr][f * 4 + 0], v[f].x);
            atomicAdd(&acc[lr][f * 4 + 1], v[f].y);
            atomicAdd(&acc[lr][f * 4 + 2], v[f].z);
            atomicAdd(&acc[lr][f * 4 + 3], v[f].w);
        }
        #pragma unroll
        for (int f = 0; f < 8; ++f) v[f] = wp[8 + f];
        #pragma unroll
        for (int f = 0; f < 8; ++f) {
            atomicAdd(&acc[lr][32 + f * 4 + 0], v[f].x);
            atomicAdd(&acc[lr][32 + f * 4 + 1], v[f].y);
            atomicAdd(&acc[lr][32 + f * 4 + 2], v[f].z);
            atomicAdd(&acc[lr][32 + f * 4 + 3], v[f].w);
        }
    }
    __syncthreads();

    int r0 = b << SHIFT;
    for (int i = t; i < WROWS * 64; i += 512) {
        int rr = i >> 6, c = i & 63;
        int gr = r0 + rr;
        if (gr < N) out[(size_t)gr * 64 + c] = acc[rr][c];
    }
}

extern "C" void kernel_launch(void* const* d_in, const int* in_sizes, int n_in,
                              void* d_out, int out_size, void* d_ws, size_t ws_size,
                              hipStream_t stream) {
    const int*   edge   = (const int*)d_in[0];     // (2,E) int32; rows = edge[0,:]
    const float* edge_w = (const float*)d_in[1];   // (E, 64) float32
    int E = in_sizes[0] / 2;
    int N = out_size / 64;
    int nblk = (E + CEDGE - 1) / CEDGE;            // 196 for E=800000
    int NB   = (N + WROWS - 1) / WROWS;            // 782 for N=50000 (<=1024)
    int M    = NB * nblk;                          // 153272
    int numTiles = (M + STILE - 1) / STILE;        // 38 (must be <=64)

    // Workspace (ints): recs[2E] | cntS[M] | cntX[M] | tileSum[64]
    int* recs    = (int*)d_ws;                     // int2[E], 8B-aligned at base
    int* cntS    = recs + 2 * (size_t)E;
    int* cntX    = cntS + M;
    int* tileSum = cntX + M;

    bucket_hist   <<<nblk, 1024, 0, stream>>>(edge, cntS, E, nblk, NB);
    scan_partial  <<<numTiles, 256, 0, stream>>>(cntS, tileSum, M);
    scan_final    <<<numTiles, 256, 0, stream>>>(cntS, tileSum, cntX, M, numTiles);
    scatter_direct<<<nblk, 1024, 0, stream>>>(edge, cntX, (int2*)recs, E, nblk, NB);
    bucket_reduce <<<NB, 512, 0, stream>>>(cntX, (const int2*)recs, 
                                           (const float4*)edge_w, (float*)d_out,
                                           E, nblk, NB, N);
}